// Round 1
// baseline (330.393 us; speedup 1.0000x reference)
//
#include <hip/hip_runtime.h>

#define E 1024
#define SEQ 2048
#define BATCH 2
#define NH 16
#define DK 64

typedef short s16x8 __attribute__((ext_vector_type(8)));
typedef float f32x4 __attribute__((ext_vector_type(4)));

static __device__ __forceinline__ unsigned short f2bf(float f) {
    union { float f; unsigned int u; } c; c.f = f;
    unsigned int u = c.u;
    return (unsigned short)((u + 0x7FFFu + ((u >> 16) & 1u)) >> 16);
}

// ---------------- weight prep: W[k][n] fp32 -> Wt[n][k] bf16 ----------------
__global__ __launch_bounds__(256) void wprep(const float* __restrict__ w,
                                             unsigned short* __restrict__ wt) {
    __shared__ float t[32][33];
    const int bx = blockIdx.x * 32;  // n0
    const int by = blockIdx.y * 32;  // k0
    const int tx = threadIdx.x & 31, ty = threadIdx.x >> 5;  // ty 0..7
    for (int i = 0; i < 32; i += 8)
        t[ty + i][tx] = w[(size_t)(by + ty + i) * E + bx + tx];
    __syncthreads();
    for (int i = 0; i < 32; i += 8)
        wt[(size_t)(bx + ty + i) * E + by + tx] = f2bf(t[tx][ty + i]);
}

// ---------------- GEMM: C[M][E] = A[M][E] @ Bt^T + bias ----------------
// Bt is [n][k] bf16.  64x64 tile, BK=32, 4 waves (each 16 rows x 64 cols).
template <int A_F32, int OUT_F32>
__global__ __launch_bounds__(256) void gemm(const void* __restrict__ Av,
                                            const unsigned short* __restrict__ Bt,
                                            const float* __restrict__ bias,
                                            void* __restrict__ Cv) {
    __shared__ __attribute__((aligned(16))) unsigned short As[64][40];
    __shared__ __attribute__((aligned(16))) unsigned short Bs[64][40];
    const int tid = threadIdx.x;
    const int w = tid >> 6, l = tid & 63, lg = l >> 4, lr = l & 15;
    const int m0 = blockIdx.y * 64, n0 = blockIdx.x * 64;

    f32x4 acc[4] = {};

    for (int k0 = 0; k0 < E; k0 += 32) {
        __syncthreads();
        {
            const int row = tid >> 2, kc = (tid & 3) * 8;
            if (A_F32) {
                const float* A = (const float*)Av;
                const float4 v0 = *(const float4*)&A[(size_t)(m0 + row) * E + k0 + kc];
                const float4 v1 = *(const float4*)&A[(size_t)(m0 + row) * E + k0 + kc + 4];
                s16x8 o8;
                o8[0] = (short)f2bf(v0.x); o8[1] = (short)f2bf(v0.y);
                o8[2] = (short)f2bf(v0.z); o8[3] = (short)f2bf(v0.w);
                o8[4] = (short)f2bf(v1.x); o8[5] = (short)f2bf(v1.y);
                o8[6] = (short)f2bf(v1.z); o8[7] = (short)f2bf(v1.w);
                *(s16x8*)&As[row][kc] = o8;
            } else {
                const unsigned short* A = (const unsigned short*)Av;
                *(s16x8*)&As[row][kc] = *(const s16x8*)&A[(size_t)(m0 + row) * E + k0 + kc];
            }
            *(s16x8*)&Bs[row][kc] = *(const s16x8*)&Bt[(size_t)(n0 + row) * E + k0 + kc];
        }
        __syncthreads();
        const s16x8 a = *(const s16x8*)&As[w * 16 + lr][lg * 8];
        for (int nt = 0; nt < 4; nt++) {
            const s16x8 b = *(const s16x8*)&Bs[nt * 16 + lr][lg * 8];
            acc[nt] = __builtin_amdgcn_mfma_f32_16x16x32_bf16(a, b, acc[nt], 0, 0, 0);
        }
    }

    for (int nt = 0; nt < 4; nt++) {
        const int n = n0 + nt * 16 + lr;
        const float bv = bias[n];
        for (int r = 0; r < 4; r++) {
            const int m = m0 + w * 16 + lg * 4 + r;
            const float v = acc[nt][r] + bv;
            if (OUT_F32) ((float*)Cv)[(size_t)m * E + n] = v;
            else ((unsigned short*)Cv)[(size_t)m * E + n] = f2bf(v);
        }
    }
}

// ---------------- flash attention with exact masked-softmax semantics -------
// scores = (Q K^T)/8 ; masked (mask==0) scores := 1e-8 BEFORE softmax.
__global__ __launch_bounds__(256) void attn(const unsigned short* __restrict__ qb,
                                            const unsigned short* __restrict__ kb,
                                            const unsigned short* __restrict__ vb,
                                            const int* __restrict__ mask,
                                            unsigned short* __restrict__ ctx) {
    __shared__ __attribute__((aligned(16))) unsigned short Kl[32][72];
    __shared__ __attribute__((aligned(16))) unsigned short Vt[64][40];
    __shared__ __attribute__((aligned(16))) unsigned short Pl[4][16][40];

    const int tid = threadIdx.x;
    const int w = tid >> 6, l = tid & 63, lg = l >> 4, lr = l & 15;
    const int qt = blockIdx.x, h = blockIdx.y, b = blockIdx.z;
    const int q0 = qt * 64 + w * 16;

    const unsigned short* qh = qb + (size_t)b * SEQ * E + h * DK;
    const unsigned short* kh = kb + (size_t)b * SEQ * E + h * DK;
    const unsigned short* vh = vb + (size_t)b * SEQ * E + h * DK;
    const int* mrow = mask + (size_t)b * SEQ * SEQ;

    s16x8 aq0 = *(const s16x8*)&qh[(size_t)(q0 + lr) * E + lg * 8];
    s16x8 aq1 = *(const s16x8*)&qh[(size_t)(q0 + lr) * E + 32 + lg * 8];

    f32x4 o[4] = {};
    float mrun[4] = {-1e30f, -1e30f, -1e30f, -1e30f};
    float lrun[4] = {0.f, 0.f, 0.f, 0.f};

    for (int k0 = 0; k0 < SEQ; k0 += 32) {
        __syncthreads();
        {
            const int row = tid >> 3, c8 = (tid & 7) * 8;
            *(s16x8*)&Kl[row][c8] = *(const s16x8*)&kh[(size_t)(k0 + row) * E + c8];
            const int vk = tid & 31, vc = (tid >> 5) * 8;
            const s16x8 vv = *(const s16x8*)&vh[(size_t)(k0 + vk) * E + vc];
            for (int j = 0; j < 8; j++) Vt[vc + j][vk] = (unsigned short)vv[j];
        }
        __syncthreads();

        f32x4 s0 = {}, s1 = {};
        {
            const s16x8 b0a = *(const s16x8*)&Kl[lr][lg * 8];
            const s16x8 b0b = *(const s16x8*)&Kl[lr][32 + lg * 8];
            s0 = __builtin_amdgcn_mfma_f32_16x16x32_bf16(aq0, b0a, s0, 0, 0, 0);
            s0 = __builtin_amdgcn_mfma_f32_16x16x32_bf16(aq1, b0b, s0, 0, 0, 0);
            const s16x8 b1a = *(const s16x8*)&Kl[16 + lr][lg * 8];
            const s16x8 b1b = *(const s16x8*)&Kl[16 + lr][32 + lg * 8];
            s1 = __builtin_amdgcn_mfma_f32_16x16x32_bf16(aq0, b1a, s1, 0, 0, 0);
            s1 = __builtin_amdgcn_mfma_f32_16x16x32_bf16(aq1, b1b, s1, 0, 0, 0);
        }

        float p0[4], p1[4], alpha[4];
        for (int r = 0; r < 4; r++) {
            const int q = q0 + lg * 4 + r;
            const int mv0 = mrow[(size_t)q * SEQ + k0 + lr];
            const int mv1 = mrow[(size_t)q * SEQ + k0 + 16 + lr];
            const float v0 = mv0 ? s0[r] * 0.125f : 1e-8f;
            const float v1 = mv1 ? s1[r] * 0.125f : 1e-8f;
            float mx = fmaxf(v0, v1);
            mx = fmaxf(mx, __shfl_xor(mx, 1));
            mx = fmaxf(mx, __shfl_xor(mx, 2));
            mx = fmaxf(mx, __shfl_xor(mx, 4));
            mx = fmaxf(mx, __shfl_xor(mx, 8));
            const float mn = fmaxf(mrun[r], mx);
            alpha[r] = __expf(mrun[r] - mn);
            mrun[r] = mn;
            p0[r] = __expf(v0 - mn);
            p1[r] = __expf(v1 - mn);
            float ps = p0[r] + p1[r];
            ps += __shfl_xor(ps, 1);
            ps += __shfl_xor(ps, 2);
            ps += __shfl_xor(ps, 4);
            ps += __shfl_xor(ps, 8);
            lrun[r] = lrun[r] * alpha[r] + ps;
        }
        for (int nt = 0; nt < 4; nt++)
            for (int r = 0; r < 4; r++) o[nt][r] *= alpha[r];

        for (int r = 0; r < 4; r++) {
            Pl[w][lg * 4 + r][lr] = f2bf(p0[r]);
            Pl[w][lg * 4 + r][16 + lr] = f2bf(p1[r]);
        }
        const s16x8 ap = *(const s16x8*)&Pl[w][lr][lg * 8];
        for (int nt = 0; nt < 4; nt++) {
            const s16x8 bvv = *(const s16x8*)&Vt[nt * 16 + lr][lg * 8];
            o[nt] = __builtin_amdgcn_mfma_f32_16x16x32_bf16(ap, bvv, o[nt], 0, 0, 0);
        }
    }

    for (int nt = 0; nt < 4; nt++) {
        for (int r = 0; r < 4; r++) {
            const int q = q0 + lg * 4 + r;
            const float v = o[nt][r] / lrun[r];
            ctx[(size_t)(b * SEQ + q) * E + h * DK + nt * 16 + lr] = f2bf(v);
        }
    }
}

extern "C" void kernel_launch(void* const* d_in, const int* in_sizes, int n_in,
                              void* d_out, int out_size, void* d_ws, size_t ws_size,
                              hipStream_t stream) {
    const float* query = (const float*)d_in[0];
    const float* key   = (const float*)d_in[1];
    const float* value = (const float*)d_in[2];
    const int*   mask  = (const int*)d_in[3];
    const float* wq = (const float*)d_in[4];
    const float* bq = (const float*)d_in[5];
    const float* wk = (const float*)d_in[6];
    const float* bk = (const float*)d_in[7];
    const float* wv = (const float*)d_in[8];
    const float* bv = (const float*)d_in[9];
    const float* wo = (const float*)d_in[10];
    const float* bo = (const float*)d_in[11];

    unsigned short* wt_q = (unsigned short*)d_ws;
    unsigned short* wt_k = wt_q + (size_t)E * E;
    unsigned short* wt_v = wt_k + (size_t)E * E;
    unsigned short* wt_o = wt_v + (size_t)E * E;
    unsigned short* qb   = wt_o + (size_t)E * E;
    unsigned short* kb   = qb + (size_t)BATCH * SEQ * E;
    unsigned short* vb   = kb + (size_t)BATCH * SEQ * E;
    unsigned short* ctx  = vb + (size_t)BATCH * SEQ * E;

    dim3 gw(E / 32, E / 32);
    wprep<<<gw, 256, 0, stream>>>(wq, wt_q);
    wprep<<<gw, 256, 0, stream>>>(wk, wt_k);
    wprep<<<gw, 256, 0, stream>>>(wv, wt_v);
    wprep<<<gw, 256, 0, stream>>>(wo, wt_o);

    dim3 gg(E / 64, (BATCH * SEQ) / 64);
    gemm<1, 0><<<gg, 256, 0, stream>>>(query, wt_q, bq, qb);
    gemm<1, 0><<<gg, 256, 0, stream>>>(key,   wt_k, bk, kb);
    gemm<1, 0><<<gg, 256, 0, stream>>>(value, wt_v, bv, vb);

    attn<<<dim3(SEQ / 64, NH, BATCH), 256, 0, stream>>>(qb, kb, vb, mask, ctx);

    gemm<0, 1><<<gg, 256, 0, stream>>>(ctx, wt_o, bo, (float*)d_out);
}